// Round 23
// baseline (154.794 us; speedup 1.0000x reference)
//
#include <hip/hip_runtime.h>
#include <hip/hip_bf16.h>

#define SEQ 2048
#define DIM 1024
#define NH  16
#define HD  64
#define SPLIT 4
#define KCOLS (SEQ / SPLIT)   // 512 k-columns per split
#define KVBLK 128             // k-cols per inner tile
#define CREF 10.0f            // fixed softmax reference (exact for any constant)

typedef __bf16 bf16_t;
typedef __bf16 bf16x4 __attribute__((ext_vector_type(4)));
typedef __bf16 bf16x8 __attribute__((ext_vector_type(8)));
typedef float  f32x4  __attribute__((ext_vector_type(4)));

#define MFMA16(a,b,c) __builtin_amdgcn_mfma_f32_16x16x32_bf16((a),(b),(c),0,0,0)

__device__ __forceinline__ void gload_lds16(const void* g, void* l) {
    __builtin_amdgcn_global_load_lds(
        (const __attribute__((address_space(1))) unsigned int*)g,
        (__attribute__((address_space(3))) unsigned int*)l, 16, 0, 0);
}

// ---------------- cos/sin tables + flag init + QKV bias concat ----------------
__global__ __launch_bounds__(256) void k_tables(const float* __restrict__ invf,
                                                const float* __restrict__ bq,
                                                const float* __restrict__ bv,
                                                float* __restrict__ cosT,
                                                float* __restrict__ sinT,
                                                float* __restrict__ bqkv,
                                                int* __restrict__ flag) {
    int id = blockIdx.x * 256 + threadIdx.x;     // 65536 total
    if (id == 0) flag[0] = 0;
    if (id < 3072)
        bqkv[id] = (id < 1024) ? bq[id] : ((id < 2048) ? 0.0f : bv[id - 2048]);
    int t = id >> 5, i = id & 31;
    float f = (float)t * invf[i];
    cosT[id] = cosf(f);
    sinT[id] = sinf(f);
}

// ---------------- fused f32->bf16 convert (blocks 0..6143) + mask check (6144..10239) ----
__global__ __launch_bounds__(256) void k_cvt_all(const float* __restrict__ x,
                                                 const float* __restrict__ Wq,
                                                 const float* __restrict__ Wk,
                                                 const float* __restrict__ Wv,
                                                 const float* __restrict__ Wo,
                                                 const float* __restrict__ mask,
                                                 bf16_t* __restrict__ Xb,
                                                 bf16_t* __restrict__ Wqkvb,
                                                 bf16_t* __restrict__ Wob,
                                                 int* __restrict__ flag) {
    int bid = blockIdx.x;
    if (bid >= 6144) {
        int id = (bid - 6144) * 256 + threadIdx.x;   // SEQ*SEQ/4
        f32x4 v = *(const f32x4*)(mask + (size_t)id * 4);
        bool nz = (v[0] != 0.f) | (v[1] != 0.f) | (v[2] != 0.f) | (v[3] != 0.f);
        if (__any(nz) && (threadIdx.x & 63) == 0) atomicOr(flag, 1);
        return;
    }
    int id = bid * 256 + threadIdx.x;            // 1572864 float4 units
    const float* src;
    bf16_t* dst;
    int off;
    if (id < 524288)       { src = x;  dst = Xb;              off = id; }
    else if (id < 786432)  { src = Wq; dst = Wqkvb;           off = id - 524288; }
    else if (id < 1048576) { src = Wk; dst = Wqkvb + 1048576; off = id - 786432; }
    else if (id < 1310720) { src = Wv; dst = Wqkvb + 2097152; off = id - 1048576; }
    else                   { src = Wo; dst = Wob;             off = id - 1310720; }
    float4 v = ((const float4*)src)[off];
    bf16x4 o;
    o[0] = (bf16_t)v.x; o[1] = (bf16_t)v.y; o[2] = (bf16_t)v.z; o[3] = (bf16_t)v.w;
    ((bf16x4*)dst)[off] = o;
}

// ---------------- m97-style NT GEMM + XCD-swizzled block ids ----------------
__global__ __launch_bounds__(256) void gemm128(const bf16_t* __restrict__ A,
                                               const bf16_t* __restrict__ W,
                                               const float* __restrict__ bias,
                                               bf16_t* __restrict__ outBf,
                                               float* __restrict__ outF,
                                               int N, int K) {
    __shared__ __align__(16) bf16_t As[2][128 * 32];
    __shared__ __align__(16) bf16_t Bs[2][128 * 32];
    int tid = threadIdx.x, wid = tid >> 6, lane = tid & 63;
    int lrow = lane >> 4, lcol = lane & 15;
    int wr = wid >> 1, wc = wid & 1;

    // XCD-aware bijective swizzle (T1)
    int orig = blockIdx.y * gridDim.x + blockIdx.x;
    int cpx = (gridDim.x * gridDim.y) >> 3;
    int swzb = (orig & 7) * cpx + (orig >> 3);
    int m0 = (swzb % gridDim.x) * 128;
    int n0 = (swzb / gridDim.x) * 128;

    int sr = wid * 32 + (lane >> 2);
    int sc = (lane & 3) * 8;
    const bf16_t* Ag = A + (size_t)(m0 + sr) * K + sc;
    const bf16_t* Wg = W + (size_t)(n0 + sr) * K + sc;

    f32x4 acc[4][4] = {};

#define STAGE(buf, k0) do { \
        gload_lds16(Ag + (k0),          &As[buf][wid * 1024]);       \
        gload_lds16(Ag + 16 * K + (k0), &As[buf][wid * 1024 + 512]); \
        gload_lds16(Wg + (k0),          &Bs[buf][wid * 1024]);       \
        gload_lds16(Wg + 16 * K + (k0), &Bs[buf][wid * 1024 + 512]); \
    } while (0)

    STAGE(0, 0);
    __syncthreads();
    int buf = 0;
    for (int k0 = 0; k0 < K; k0 += 32) {
        if (k0 + 32 < K) STAGE(buf ^ 1, k0 + 32);
        bf16x8 af[4], bfr[4];
#pragma unroll
        for (int mi = 0; mi < 4; mi++)
            af[mi] = *(const bf16x8*)&As[buf][(wr * 64 + mi * 16 + lcol) * 32 + lrow * 8];
#pragma unroll
        for (int ni = 0; ni < 4; ni++)
            bfr[ni] = *(const bf16x8*)&Bs[buf][(wc * 64 + ni * 16 + lcol) * 32 + lrow * 8];
#pragma unroll
        for (int mi = 0; mi < 4; mi++)
#pragma unroll
            for (int ni = 0; ni < 4; ni++)
                acc[mi][ni] = MFMA16(af[mi], bfr[ni], acc[mi][ni]);
        __syncthreads();
        buf ^= 1;
    }
#undef STAGE
#pragma unroll
    for (int ni = 0; ni < 4; ni++) {
        int col = n0 + wc * 64 + ni * 16 + lcol;
        float bb = bias ? bias[col] : 0.0f;
#pragma unroll
        for (int mi = 0; mi < 4; mi++)
#pragma unroll
            for (int j = 0; j < 4; j++) {
                int row = m0 + wr * 64 + mi * 16 + lrow * 4 + j;
                float v = acc[mi][ni][j] + bb;
                if (outBf) outBf[(size_t)row * N + col] = (bf16_t)v;
                else       outF [(size_t)row * N + col] = v;
            }
    }
}

// ---------------- fused RoPE (blocks 0..4095) + V transpose (4096..4607) ----------------
__global__ __launch_bounds__(256) void k_ropeT(const bf16_t* __restrict__ QKV,
                                               const float* __restrict__ cosT,
                                               const float* __restrict__ sinT,
                                               const float* __restrict__ Zf,
                                               bf16_t* __restrict__ Qh,
                                               bf16_t* __restrict__ Kh,
                                               float* __restrict__ zsq,
                                               bf16_t* __restrict__ Vt) {
    __shared__ bf16_t tile[64][66];
    int bid = blockIdx.x;
    if (bid >= 4096) {
        // V transpose: Vt[D][S] <- QKV V-slice [S][D]
        int tb = bid - 4096;
        int t = threadIdx.x;
        int c = t & 63, r4 = t >> 6;
        int s0 = (tb & 31) * 64, d0 = (tb >> 5) * 64;
#pragma unroll
        for (int i = 0; i < 16; i++) {
            int r = i * 4 + r4;
            tile[r][c] = QKV[(size_t)(s0 + r) * 3072 + 2048 + d0 + c];
        }
        __syncthreads();
#pragma unroll
        for (int i = 0; i < 16; i++) {
            int r = i * 4 + r4;   // d index within tile
            Vt[(size_t)(d0 + r) * SEQ + s0 + c] = tile[c][r];
        }
        return;
    }
    int id = bid * 256 + threadIdx.x;             // 2048*512
    int s = id >> 9, pp = id & 511;
    int h = pp >> 5, i = pp & 31;
    float c  = cosT[s * 32 + i];
    float sn = sinT[s * 32 + i];
    const float scale = 0.3535533905932738f;      // 64^-0.25
    size_t qb = (size_t)s * 3072 + h * HD + 2 * i;  // Q slice
    size_t kb = qb + 1024;                          // K slice
    size_t ob = ((size_t)h * SEQ + s) * HD + 2 * i; // head-major out

    float qa = (float)QKV[qb], qbv = (float)QKV[qb + 1];
    Qh[ob]     = (bf16_t)((qa * c - qbv * sn) * scale);
    Qh[ob + 1] = (bf16_t)((qa * sn + qbv * c) * scale);

    // zscale from rotated k[...,0] of this (h,s)
    float k0a = (float)QKV[(size_t)s * 3072 + 1024 + h * HD];
    float k0b = (float)QKV[(size_t)s * 3072 + 1024 + h * HD + 1];
    float ra0 = k0a * cosT[s * 32] - k0b * sinT[s * 32];
    float z = Zf[0];
    float zfac = fminf(fmaxf(log1pf(__expf(z)), 1e-5f), 1e-4f);
    float zs = (ra0 == 0.0f) ? zfac : 1.0f;

    float ka = (float)QKV[kb], kbv = (float)QKV[kb + 1];
    float ra = ka * c - kbv * sn;
    float rb = ka * sn + kbv * c;
    Kh[ob]     = (bf16_t)(ra * scale * zs);
    Kh[ob + 1] = (bf16_t)(rb * scale * zs);
    if (i == 0) zsq[h * SEQ + s] = zs * zs;
}

// ---------------- fused attention: 32KB LDS, stores issued BEFORE PV ----------------
// r22 + one reorder: qk stores issue right after the exp->LDS phase, so the 16 PV
// MFMAs (~600cy) cover the store round-trip and the end-of-iter barrier's implicit
// vmcnt(0) finds them already complete.
__global__ __launch_bounds__(256) void k_attn(const bf16_t* __restrict__ Qh,
                                              const bf16_t* __restrict__ Kh,
                                              const bf16_t* __restrict__ Vt,
                                              const float* __restrict__ mask,
                                              const float* __restrict__ zsq,
                                              const int* __restrict__ mflag,
                                              float* __restrict__ qk_out,
                                              bf16_t* __restrict__ Opart,
                                              float* __restrict__ Lpart) {
    __shared__ __align__(16) char Ks[16384];       // swizzled K tile; P tile after QK^T
    __shared__ __align__(16) char Vs[16384];       // swizzled V tile
    int tid = threadIdx.x, wid = tid >> 6, lane = tid & 63;
    int lrow = lane >> 4, lcol = lane & 15;

    // XCD-aware bijective swizzle: xcd = orig&7 owns s in [xcd*256, xcd*256+256);
    // h = s>>7 -> each XCD serves exactly 2 heads (1MB K/V, L2-resident).
    int orig = blockIdx.x;
    int s = (orig & 7) * 256 + (orig >> 3);
    int h = s >> 7;
    int rem = s & 127;
    int qblk = rem & 31, sp = rem >> 5;

    int q0 = qblk * 64 + wid * 16;
    int kbase = sp * KCOLS;
    int mz = mflag[0];                  // wave-uniform

    bf16x8 aq[2];
    {
        const bf16_t* qb = Qh + ((size_t)h * SEQ + q0 + lcol) * HD + lrow * 8;
        aq[0] = *(const bf16x8*)qb;
        aq[1] = *(const bf16x8*)(qb + 32);
    }

    float l = 0.f;
    f32x4 acc[4] = {};                  // O[q=lcol][ng*16 + lrow*4 + j]
    char* wl = Ks + wid * 4096;         // per-wave P tile, aliases dead K tile
    float* qkbase = qk_out + (size_t)h * SEQ * SEQ;
    const float* mrow = mask + (size_t)(q0 + lcol) * SEQ;
    const bf16_t* khead = Kh + (size_t)h * SEQ * HD;
    const bf16_t* vthead = Vt + (size_t)h * HD * SEQ;
    const float*  zrow  = zsq + h * SEQ;
    int swzP = (lcol & 7) << 4;
    int l7 = lcol & 7;                  // == row&7 for all frag rows (rows = x*16 + lcol)

    // staging lane constants (per issue i, dest byte o within tile)
    int so[4], krk[4], ksk[4], vrv[4], vsv[4];
#pragma unroll
    for (int i = 0; i < 4; i++) {
        int o = wid * 4096 + i * 1024 + lane * 16;
        so[i] = wid * 4096 + i * 1024;
        krk[i] = o >> 7;
        ksk[i] = ((o >> 4) & 7) ^ (krk[i] & 7);
        vrv[i] = o >> 8;
        int cv = (o >> 4) & 15;
        vsv[i] = (cv & 8) | ((cv & 7) ^ (vrv[i] & 7));
    }

    for (int kc = kbase; kc < kbase + KCOLS; kc += KVBLK) {
        // ---- stage K and V tiles (8 gload_lds per wave) ----
#pragma unroll
        for (int i = 0; i < 4; i++) {
            gload_lds16(khead + (size_t)(kc + krk[i]) * HD + ksk[i] * 8, Ks + so[i]);
            gload_lds16(vthead + (size_t)vrv[i] * SEQ + kc + vsv[i] * 8,  Vs + so[i]);
        }
        __syncthreads();   // staging drained (implicit vmcnt(0))

        // ---- QK^T from LDS (swapped): p[ct][j] = S[q=lcol][k=kc+ct*16+lrow*4+j] ----
        float p[8][4];
#pragma unroll
        for (int ct = 0; ct < 8; ct++) {
            int row = ct * 16 + lcol;
            int a0 = row * 128 + ((lrow ^ l7) << 4);
            bf16x8 k0 = *(const bf16x8*)(Ks + a0);
            bf16x8 k1 = *(const bf16x8*)(Ks + (a0 ^ 64));
            f32x4 cacc = {};
            cacc = MFMA16(k0, aq[0], cacc);
            cacc = MFMA16(k1, aq[1], cacc);
#pragma unroll
            for (int j = 0; j < 4; j++) p[ct][j] = cacc[j];
        }
        // ---- mask fma only if mask is nonzero (uniform branch) ----
        if (mz) {
#pragma unroll
            for (int ct = 0; ct < 8; ct++) {
                int k4 = kc + ct * 16 + lrow * 4;
                f32x4 mv = *(const f32x4*)(mrow + k4);
                f32x4 zv = *(const f32x4*)(zrow + k4);
#pragma unroll
                for (int j = 0; j < 4; j++)
                    p[ct][j] = fmaf(mv[j], zv[j], p[ct][j]);
            }
        }
        __syncthreads();   // all waves done reading K tile (LDS-only drain, cheap)

        // ---- exp -> P tile over dead Ks (bf16x4 per ct), accumulate l ----
#pragma unroll
        for (int ct = 0; ct < 8; ct++) {
            bf16x4 pk;
#pragma unroll
            for (int j = 0; j < 4; j++) {
                float e = __expf(p[ct][j] - CREF);
                l += e;
                pk[j] = (bf16_t)e;
            }
            int addr = (lcol << 8) + ((ct * 16 + lrow * 4) << 1);
            *(bf16x4*)(wl + (addr ^ swzP)) = pk;
        }
        // ---- qk f32 stores issued NOW: PV MFMAs below cover their latency ----
#pragma unroll
        for (int ct = 0; ct < 8; ct++) {
            int k4 = kc + ct * 16 + lrow * 4;
            f32x4 ov;
#pragma unroll
            for (int j = 0; j < 4; j++) ov[j] = p[ct][j];
            *(f32x4*)(qkbase + (size_t)(q0 + lcol) * SEQ + k4) = ov;
        }
        // ---- P fragments: lane reads P[q=lcol][ks*32 + lrow*8 ..+7] ----
        bf16x8 pa[4];
#pragma unroll
        for (int ks = 0; ks < 4; ks++) {
            int addr = (lcol << 8) + (ks << 6) + (lrow << 4);
            pa[ks] = *(const bf16x8*)(wl + (addr ^ swzP));
        }
        // ---- PV from LDS (swapped): acc[ng] += Vs-frag x P-frag ----
        __builtin_amdgcn_s_setprio(1);
#pragma unroll
        for (int ks = 0; ks < 4; ks++) {
            int c = ks * 4 + lrow;
            int cs = (c & 8) | ((c & 7) ^ l7);
#pragma unroll
            for (int ng = 0; ng < 4; ng++) {
                int a = (ng * 16 + lcol) * 256 + (cs << 4);
                bf16x8 bv = *(const bf16x8*)(Vs + a);
                acc[ng] = MFMA16(bv, pa[ks], acc[ng]);
            }
        }
        __builtin_amdgcn_s_setprio(0);
        __syncthreads();   // all waves done with P(Ks)/Vs before next stage (WAR)
    }
    // ---- split partials: lane holds O[q=lcol][ng*16+lrow*4+j] ----
#pragma unroll
    for (int ng = 0; ng < 4; ng++) {
        bf16x4 o4;
#pragma unroll
        for (int j = 0; j < 4; j++) o4[j] = (bf16_t)acc[ng][j];
        size_t idx = ((size_t)(h * SEQ + q0 + lcol) * SPLIT + sp) * HD + ng * 16 + lrow * 4;
        *(bf16x4*)(Opart + idx) = o4;
    }
    l += __shfl_xor(l, 16);
    l += __shfl_xor(l, 32);
    if (lane < 16) {
        Lpart[((size_t)h * SEQ + q0 + lane) * SPLIT + sp] = l;
    }
}

// ---------------- combine: exact sums (shared CREF), normalize ----------------
__global__ __launch_bounds__(256) void k_combine(const bf16_t* __restrict__ Opart,
                                                 const float* __restrict__ Lpart,
                                                 bf16_t* __restrict__ wv) {
    int gid = blockIdx.x * 256 + threadIdx.x;     // NH*SEQ*64
    int rowIdx = gid >> 6, d = gid & 63;
    const float* lp = Lpart + (size_t)rowIdx * SPLIT;
    float L = 0.f, O = 0.f;
    const bf16_t* ob = Opart + (size_t)rowIdx * SPLIT * HD + d;
#pragma unroll
    for (int s = 0; s < SPLIT; s++) {
        L += lp[s];
        O += (float)ob[(size_t)s * HD];
    }
    int h = rowIdx >> 11, row = rowIdx & (SEQ - 1);
    wv[(size_t)row * DIM + h * HD + d] = (bf16_t)(O / L);
}

extern "C" void kernel_launch(void* const* d_in, const int* in_sizes, int n_in,
                              void* d_out, int out_size, void* d_ws, size_t ws_size,
                              hipStream_t stream) {
    const float* x    = (const float*)d_in[0];
    const float* mask = (const float*)d_in[1];
    const float* Wq   = (const float*)d_in[2];
    const float* bq   = (const float*)d_in[3];
    const float* Wk   = (const float*)d_in[4];
    const float* Wv   = (const float*)d_in[5];
    const float* bv   = (const float*)d_in[6];
    const float* Wo   = (const float*)d_in[7];
    const float* bo   = (const float*)d_in[8];
    const float* Zf   = (const float*)d_in[9];
    const float* invf = (const float*)d_in[10];

    char* ws = (char*)d_ws;
    size_t off = 0;
    auto alloc = [&](size_t bytes) -> char* {
        char* p = ws + off;
        off += (bytes + 255) & ~(size_t)255;
        return p;
    };
    float*  cosT  = (float*)alloc(65536 * 4);
    float*  sinT  = (float*)alloc(65536 * 4);
    bf16_t* Xb    = (bf16_t*)alloc((size_t)SEQ * DIM * 2);
    bf16_t* Wqkvb = (bf16_t*)alloc((size_t)3 * DIM * DIM * 2);
    bf16_t* Wob   = (bf16_t*)alloc((size_t)DIM * DIM * 2);
    float*  bqkv  = (float*)alloc(3072 * 4);
    bf16_t* QKV   = (bf16_t*)alloc((size_t)SEQ * 3 * DIM * 2);
    bf16_t* Qhp   = (bf16_t*)alloc((size_t)SEQ * DIM * 2);
    bf16_t* Khp   = (bf16_t*)alloc((size_t)SEQ * DIM * 2);
    bf16_t* Vt    = (bf16_t*)alloc((size_t)DIM * SEQ * 2);
    float*  zsq   = (float*)alloc((size_t)NH * SEQ * 4);
    bf16_t* Opart = (bf16_t*)alloc((size_t)NH * SEQ * SPLIT * HD * 2);
    float*  Lpart = (float*)alloc((size_t)NH * SEQ * SPLIT * 4);
    bf16_t* WVb   = (bf16_t*)alloc((size_t)SEQ * DIM * 2);
    int*    mflag = (int*)alloc(256);

    float* outp = (float*)d_out;
    float* qkp  = outp + (size_t)SEQ * DIM;   // out is 2048*1024, then qk 16*2048*2048

    k_tables<<<256, 256, 0, stream>>>(invf, bq, bv, cosT, sinT, bqkv, mflag);
    k_cvt_all<<<10240, 256, 0, stream>>>(x, Wq, Wk, Wv, Wo, mask, Xb, Wqkvb, Wob, mflag);

    // fused QKV projection: [2048][3072]
    gemm128<<<dim3(SEQ / 128, 3072 / 128), 256, 0, stream>>>(Xb, Wqkvb, bqkv, QKV, nullptr, 3072, DIM);

    k_ropeT<<<4608, 256, 0, stream>>>(QKV, cosT, sinT, Zf, Qhp, Khp, zsq, Vt);

    k_attn<<<NH * (SEQ / 64) * SPLIT, 256, 0, stream>>>(Qhp, Khp, Vt, mask, zsq, mflag,
                                                        qkp, Opart, Lpart);
    k_combine<<<(NH * SEQ * HD) / 256, 256, 0, stream>>>(Opart, Lpart, WVb);

    // output projection (f32 out)
    gemm128<<<dim3(SEQ / 128, DIM / 128), 256, 0, stream>>>(WVb, Wob, bo, nullptr, outp, DIM, DIM);
}

// Round 24
// 150.810 us; speedup vs baseline: 1.0264x; 1.0264x over previous
//
#include <hip/hip_runtime.h>
#include <hip/hip_bf16.h>

#define SEQ 2048
#define DIM 1024
#define NH  16
#define HD  64
#define SPLIT 4
#define KCOLS (SEQ / SPLIT)   // 512 k-columns per split
#define KVBLK 128             // k-cols per inner tile
#define CREF 10.0f            // fixed softmax reference (exact for any constant)

typedef __bf16 bf16_t;
typedef __bf16 bf16x4 __attribute__((ext_vector_type(4)));
typedef __bf16 bf16x8 __attribute__((ext_vector_type(8)));
typedef float  f32x4  __attribute__((ext_vector_type(4)));

#define MFMA16(a,b,c) __builtin_amdgcn_mfma_f32_16x16x32_bf16((a),(b),(c),0,0,0)

__device__ __forceinline__ void gload_lds16(const void* g, void* l) {
    __builtin_amdgcn_global_load_lds(
        (const __attribute__((address_space(1))) unsigned int*)g,
        (__attribute__((address_space(3))) unsigned int*)l, 16, 0, 0);
}

// ---------------- cos/sin tables + flag init + QKV bias concat ----------------
__global__ __launch_bounds__(256) void k_tables(const float* __restrict__ invf,
                                                const float* __restrict__ bq,
                                                const float* __restrict__ bv,
                                                float* __restrict__ cosT,
                                                float* __restrict__ sinT,
                                                float* __restrict__ bqkv,
                                                int* __restrict__ flag) {
    int id = blockIdx.x * 256 + threadIdx.x;     // 65536 total
    if (id == 0) flag[0] = 0;
    if (id < 3072)
        bqkv[id] = (id < 1024) ? bq[id] : ((id < 2048) ? 0.0f : bv[id - 2048]);
    int t = id >> 5, i = id & 31;
    float f = (float)t * invf[i];
    cosT[id] = cosf(f);
    sinT[id] = sinf(f);
}

// ---------------- fused f32->bf16 convert (blocks 0..6143) + mask check (6144..10239) ----
__global__ __launch_bounds__(256) void k_cvt_all(const float* __restrict__ x,
                                                 const float* __restrict__ Wq,
                                                 const float* __restrict__ Wk,
                                                 const float* __restrict__ Wv,
                                                 const float* __restrict__ Wo,
                                                 const float* __restrict__ mask,
                                                 bf16_t* __restrict__ Xb,
                                                 bf16_t* __restrict__ Wqkvb,
                                                 bf16_t* __restrict__ Wob,
                                                 int* __restrict__ flag) {
    int bid = blockIdx.x;
    if (bid >= 6144) {
        int id = (bid - 6144) * 256 + threadIdx.x;   // SEQ*SEQ/4
        f32x4 v = *(const f32x4*)(mask + (size_t)id * 4);
        bool nz = (v[0] != 0.f) | (v[1] != 0.f) | (v[2] != 0.f) | (v[3] != 0.f);
        if (__any(nz) && (threadIdx.x & 63) == 0) atomicOr(flag, 1);
        return;
    }
    int id = bid * 256 + threadIdx.x;            // 1572864 float4 units
    const float* src;
    bf16_t* dst;
    int off;
    if (id < 524288)       { src = x;  dst = Xb;              off = id; }
    else if (id < 786432)  { src = Wq; dst = Wqkvb;           off = id - 524288; }
    else if (id < 1048576) { src = Wk; dst = Wqkvb + 1048576; off = id - 786432; }
    else if (id < 1310720) { src = Wv; dst = Wqkvb + 2097152; off = id - 1048576; }
    else                   { src = Wo; dst = Wob;             off = id - 1310720; }
    float4 v = ((const float4*)src)[off];
    bf16x4 o;
    o[0] = (bf16_t)v.x; o[1] = (bf16_t)v.y; o[2] = (bf16_t)v.z; o[3] = (bf16_t)v.w;
    ((bf16x4*)dst)[off] = o;
}

// ---------------- m97-style NT GEMM + XCD-swizzled block ids ----------------
__global__ __launch_bounds__(256) void gemm128(const bf16_t* __restrict__ A,
                                               const bf16_t* __restrict__ W,
                                               const float* __restrict__ bias,
                                               bf16_t* __restrict__ outBf,
                                               float* __restrict__ outF,
                                               int N, int K) {
    __shared__ __align__(16) bf16_t As[2][128 * 32];
    __shared__ __align__(16) bf16_t Bs[2][128 * 32];
    int tid = threadIdx.x, wid = tid >> 6, lane = tid & 63;
    int lrow = lane >> 4, lcol = lane & 15;
    int wr = wid >> 1, wc = wid & 1;

    // XCD-aware bijective swizzle (T1)
    int orig = blockIdx.y * gridDim.x + blockIdx.x;
    int cpx = (gridDim.x * gridDim.y) >> 3;
    int swzb = (orig & 7) * cpx + (orig >> 3);
    int m0 = (swzb % gridDim.x) * 128;
    int n0 = (swzb / gridDim.x) * 128;

    int sr = wid * 32 + (lane >> 2);
    int sc = (lane & 3) * 8;
    const bf16_t* Ag = A + (size_t)(m0 + sr) * K + sc;
    const bf16_t* Wg = W + (size_t)(n0 + sr) * K + sc;

    f32x4 acc[4][4] = {};

#define STAGE(buf, k0) do { \
        gload_lds16(Ag + (k0),          &As[buf][wid * 1024]);       \
        gload_lds16(Ag + 16 * K + (k0), &As[buf][wid * 1024 + 512]); \
        gload_lds16(Wg + (k0),          &Bs[buf][wid * 1024]);       \
        gload_lds16(Wg + 16 * K + (k0), &Bs[buf][wid * 1024 + 512]); \
    } while (0)

    STAGE(0, 0);
    __syncthreads();
    int buf = 0;
    for (int k0 = 0; k0 < K; k0 += 32) {
        if (k0 + 32 < K) STAGE(buf ^ 1, k0 + 32);
        bf16x8 af[4], bfr[4];
#pragma unroll
        for (int mi = 0; mi < 4; mi++)
            af[mi] = *(const bf16x8*)&As[buf][(wr * 64 + mi * 16 + lcol) * 32 + lrow * 8];
#pragma unroll
        for (int ni = 0; ni < 4; ni++)
            bfr[ni] = *(const bf16x8*)&Bs[buf][(wc * 64 + ni * 16 + lcol) * 32 + lrow * 8];
#pragma unroll
        for (int mi = 0; mi < 4; mi++)
#pragma unroll
            for (int ni = 0; ni < 4; ni++)
                acc[mi][ni] = MFMA16(af[mi], bfr[ni], acc[mi][ni]);
        __syncthreads();
        buf ^= 1;
    }
#undef STAGE
#pragma unroll
    for (int ni = 0; ni < 4; ni++) {
        int col = n0 + wc * 64 + ni * 16 + lcol;
        float bb = bias ? bias[col] : 0.0f;
#pragma unroll
        for (int mi = 0; mi < 4; mi++)
#pragma unroll
            for (int j = 0; j < 4; j++) {
                int row = m0 + wr * 64 + mi * 16 + lrow * 4 + j;
                float v = acc[mi][ni][j] + bb;
                if (outBf) outBf[(size_t)row * N + col] = (bf16_t)v;
                else       outF [(size_t)row * N + col] = v;
            }
    }
}

// ---------------- fused RoPE (blocks 0..4095) + V transpose (4096..4607) ----------------
__global__ __launch_bounds__(256) void k_ropeT(const bf16_t* __restrict__ QKV,
                                               const float* __restrict__ cosT,
                                               const float* __restrict__ sinT,
                                               const float* __restrict__ Zf,
                                               bf16_t* __restrict__ Qh,
                                               bf16_t* __restrict__ Kh,
                                               float* __restrict__ zsq,
                                               bf16_t* __restrict__ Vt) {
    __shared__ bf16_t tile[64][66];
    int bid = blockIdx.x;
    if (bid >= 4096) {
        // V transpose: Vt[D][S] <- QKV V-slice [S][D]
        int tb = bid - 4096;
        int t = threadIdx.x;
        int c = t & 63, r4 = t >> 6;
        int s0 = (tb & 31) * 64, d0 = (tb >> 5) * 64;
#pragma unroll
        for (int i = 0; i < 16; i++) {
            int r = i * 4 + r4;
            tile[r][c] = QKV[(size_t)(s0 + r) * 3072 + 2048 + d0 + c];
        }
        __syncthreads();
#pragma unroll
        for (int i = 0; i < 16; i++) {
            int r = i * 4 + r4;   // d index within tile
            Vt[(size_t)(d0 + r) * SEQ + s0 + c] = tile[c][r];
        }
        return;
    }
    int id = bid * 256 + threadIdx.x;             // 2048*512
    int s = id >> 9, pp = id & 511;
    int h = pp >> 5, i = pp & 31;
    float c  = cosT[s * 32 + i];
    float sn = sinT[s * 32 + i];
    const float scale = 0.3535533905932738f;      // 64^-0.25
    size_t qb = (size_t)s * 3072 + h * HD + 2 * i;  // Q slice
    size_t kb = qb + 1024;                          // K slice
    size_t ob = ((size_t)h * SEQ + s) * HD + 2 * i; // head-major out

    float qa = (float)QKV[qb], qbv = (float)QKV[qb + 1];
    Qh[ob]     = (bf16_t)((qa * c - qbv * sn) * scale);
    Qh[ob + 1] = (bf16_t)((qa * sn + qbv * c) * scale);

    // zscale from rotated k[...,0] of this (h,s)
    float k0a = (float)QKV[(size_t)s * 3072 + 1024 + h * HD];
    float k0b = (float)QKV[(size_t)s * 3072 + 1024 + h * HD + 1];
    float ra0 = k0a * cosT[s * 32] - k0b * sinT[s * 32];
    float z = Zf[0];
    float zfac = fminf(fmaxf(log1pf(__expf(z)), 1e-5f), 1e-4f);
    float zs = (ra0 == 0.0f) ? zfac : 1.0f;

    float ka = (float)QKV[kb], kbv = (float)QKV[kb + 1];
    float ra = ka * c - kbv * sn;
    float rb = ka * sn + kbv * c;
    Kh[ob]     = (bf16_t)(ra * scale * zs);
    Kh[ob + 1] = (bf16_t)(rb * scale * zs);
    if (i == 0) zsq[h * SEQ + s] = zs * zs;
}

// ---------------- fused attention: 32KB LDS (P aliases dead K tile) + XCD heads ----------
// Final config (r22, best measured): single-buffer staging, 5 blocks/CU, stores after PV.
__global__ __launch_bounds__(256) void k_attn(const bf16_t* __restrict__ Qh,
                                              const bf16_t* __restrict__ Kh,
                                              const bf16_t* __restrict__ Vt,
                                              const float* __restrict__ mask,
                                              const float* __restrict__ zsq,
                                              const int* __restrict__ mflag,
                                              float* __restrict__ qk_out,
                                              bf16_t* __restrict__ Opart,
                                              float* __restrict__ Lpart) {
    __shared__ __align__(16) char Ks[16384];       // swizzled K tile; P tile after QK^T
    __shared__ __align__(16) char Vs[16384];       // swizzled V tile
    int tid = threadIdx.x, wid = tid >> 6, lane = tid & 63;
    int lrow = lane >> 4, lcol = lane & 15;

    // XCD-aware bijective swizzle: xcd = orig&7 owns s in [xcd*256, xcd*256+256);
    // h = s>>7 -> each XCD serves exactly 2 heads (1MB K/V, L2-resident).
    int orig = blockIdx.x;
    int s = (orig & 7) * 256 + (orig >> 3);
    int h = s >> 7;
    int rem = s & 127;
    int qblk = rem & 31, sp = rem >> 5;

    int q0 = qblk * 64 + wid * 16;
    int kbase = sp * KCOLS;
    int mz = mflag[0];                  // wave-uniform

    bf16x8 aq[2];
    {
        const bf16_t* qb = Qh + ((size_t)h * SEQ + q0 + lcol) * HD + lrow * 8;
        aq[0] = *(const bf16x8*)qb;
        aq[1] = *(const bf16x8*)(qb + 32);
    }

    float l = 0.f;
    f32x4 acc[4] = {};                  // O[q=lcol][ng*16 + lrow*4 + j]
    char* wl = Ks + wid * 4096;         // per-wave P tile, aliases dead K tile
    float* qkbase = qk_out + (size_t)h * SEQ * SEQ;
    const float* mrow = mask + (size_t)(q0 + lcol) * SEQ;
    const bf16_t* khead = Kh + (size_t)h * SEQ * HD;
    const bf16_t* vthead = Vt + (size_t)h * HD * SEQ;
    const float*  zrow  = zsq + h * SEQ;
    int swzP = (lcol & 7) << 4;
    int l7 = lcol & 7;                  // == row&7 for all frag rows (rows = x*16 + lcol)

    // staging lane constants (per issue i, dest byte o within tile)
    int so[4], krk[4], ksk[4], vrv[4], vsv[4];
#pragma unroll
    for (int i = 0; i < 4; i++) {
        int o = wid * 4096 + i * 1024 + lane * 16;
        so[i] = wid * 4096 + i * 1024;
        krk[i] = o >> 7;
        ksk[i] = ((o >> 4) & 7) ^ (krk[i] & 7);
        vrv[i] = o >> 8;
        int cv = (o >> 4) & 15;
        vsv[i] = (cv & 8) | ((cv & 7) ^ (vrv[i] & 7));
    }

    for (int kc = kbase; kc < kbase + KCOLS; kc += KVBLK) {
        // ---- stage K and V tiles (8 gload_lds per wave) ----
#pragma unroll
        for (int i = 0; i < 4; i++) {
            gload_lds16(khead + (size_t)(kc + krk[i]) * HD + ksk[i] * 8, Ks + so[i]);
            gload_lds16(vthead + (size_t)vrv[i] * SEQ + kc + vsv[i] * 8,  Vs + so[i]);
        }
        __syncthreads();   // staging drained (implicit vmcnt(0))

        // ---- QK^T from LDS (swapped): p[ct][j] = S[q=lcol][k=kc+ct*16+lrow*4+j] ----
        float p[8][4];
#pragma unroll
        for (int ct = 0; ct < 8; ct++) {
            int row = ct * 16 + lcol;
            int a0 = row * 128 + ((lrow ^ l7) << 4);
            bf16x8 k0 = *(const bf16x8*)(Ks + a0);
            bf16x8 k1 = *(const bf16x8*)(Ks + (a0 ^ 64));
            f32x4 cacc = {};
            cacc = MFMA16(k0, aq[0], cacc);
            cacc = MFMA16(k1, aq[1], cacc);
#pragma unroll
            for (int j = 0; j < 4; j++) p[ct][j] = cacc[j];
        }
        // ---- mask fma only if mask is nonzero (uniform branch) ----
        if (mz) {
#pragma unroll
            for (int ct = 0; ct < 8; ct++) {
                int k4 = kc + ct * 16 + lrow * 4;
                f32x4 mv = *(const f32x4*)(mrow + k4);
                f32x4 zv = *(const f32x4*)(zrow + k4);
#pragma unroll
                for (int j = 0; j < 4; j++)
                    p[ct][j] = fmaf(mv[j], zv[j], p[ct][j]);
            }
        }
        __syncthreads();   // all waves done reading K tile (LDS-only drain, cheap)

        // ---- exp -> P tile over dead Ks (bf16x4 per ct), accumulate l ----
#pragma unroll
        for (int ct = 0; ct < 8; ct++) {
            bf16x4 pk;
#pragma unroll
            for (int j = 0; j < 4; j++) {
                float e = __expf(p[ct][j] - CREF);
                l += e;
                pk[j] = (bf16_t)e;
            }
            int addr = (lcol << 8) + ((ct * 16 + lrow * 4) << 1);
            *(bf16x4*)(wl + (addr ^ swzP)) = pk;
        }
        // ---- P fragments: lane reads P[q=lcol][ks*32 + lrow*8 ..+7] ----
        bf16x8 pa[4];
#pragma unroll
        for (int ks = 0; ks < 4; ks++) {
            int addr = (lcol << 8) + (ks << 6) + (lrow << 4);
            pa[ks] = *(const bf16x8*)(wl + (addr ^ swzP));
        }
        // ---- PV from LDS (swapped): acc[ng] += Vs-frag x P-frag ----
        __builtin_amdgcn_s_setprio(1);
#pragma unroll
        for (int ks = 0; ks < 4; ks++) {
            int c = ks * 4 + lrow;
            int cs = (c & 8) | ((c & 7) ^ l7);
#pragma unroll
            for (int ng = 0; ng < 4; ng++) {
                int a = (ng * 16 + lcol) * 256 + (cs << 4);
                bf16x8 bv = *(const bf16x8*)(Vs + a);
                acc[ng] = MFMA16(bv, pa[ks], acc[ng]);
            }
        }
        __builtin_amdgcn_s_setprio(0);
        // ---- qk f32 stores ----
#pragma unroll
        for (int ct = 0; ct < 8; ct++) {
            int k4 = kc + ct * 16 + lrow * 4;
            f32x4 ov;
#pragma unroll
            for (int j = 0; j < 4; j++) ov[j] = p[ct][j];
            *(f32x4*)(qkbase + (size_t)(q0 + lcol) * SEQ + k4) = ov;
        }
        __syncthreads();   // all waves done with P(Ks)/Vs before next stage (WAR)
    }
    // ---- split partials: lane holds O[q=lcol][ng*16+lrow*4+j] ----
#pragma unroll
    for (int ng = 0; ng < 4; ng++) {
        bf16x4 o4;
#pragma unroll
        for (int j = 0; j < 4; j++) o4[j] = (bf16_t)acc[ng][j];
        size_t idx = ((size_t)(h * SEQ + q0 + lcol) * SPLIT + sp) * HD + ng * 16 + lrow * 4;
        *(bf16x4*)(Opart + idx) = o4;
    }
    l += __shfl_xor(l, 16);
    l += __shfl_xor(l, 32);
    if (lane < 16) {
        Lpart[((size_t)h * SEQ + q0 + lane) * SPLIT + sp] = l;
    }
}

// ---------------- combine: exact sums (shared CREF), normalize ----------------
__global__ __launch_bounds__(256) void k_combine(const bf16_t* __restrict__ Opart,
                                                 const float* __restrict__ Lpart,
                                                 bf16_t* __restrict__ wv) {
    int gid = blockIdx.x * 256 + threadIdx.x;     // NH*SEQ*64
    int rowIdx = gid >> 6, d = gid & 63;
    const float* lp = Lpart + (size_t)rowIdx * SPLIT;
    float L = 0.f, O = 0.f;
    const bf16_t* ob = Opart + (size_t)rowIdx * SPLIT * HD + d;
#pragma unroll
    for (int s = 0; s < SPLIT; s++) {
        L += lp[s];
        O += (float)ob[(size_t)s * HD];
    }
    int h = rowIdx >> 11, row = rowIdx & (SEQ - 1);
    wv[(size_t)row * DIM + h * HD + d] = (bf16_t)(O / L);
}

extern "C" void kernel_launch(void* const* d_in, const int* in_sizes, int n_in,
                              void* d_out, int out_size, void* d_ws, size_t ws_size,
                              hipStream_t stream) {
    const float* x    = (const float*)d_in[0];
    const float* mask = (const float*)d_in[1];
    const float* Wq   = (const float*)d_in[2];
    const float* bq   = (const float*)d_in[3];
    const float* Wk   = (const float*)d_in[4];
    const float* Wv   = (const float*)d_in[5];
    const float* bv   = (const float*)d_in[6];
    const float* Wo   = (const float*)d_in[7];
    const float* bo   = (const float*)d_in[8];
    const float* Zf   = (const float*)d_in[9];
    const float* invf = (const float*)d_in[10];

    char* ws = (char*)d_ws;
    size_t off = 0;
    auto alloc = [&](size_t bytes) -> char* {
        char* p = ws + off;
        off += (bytes + 255) & ~(size_t)255;
        return p;
    };
    float*  cosT  = (float*)alloc(65536 * 4);
    float*  sinT  = (float*)alloc(65536 * 4);
    bf16_t* Xb    = (bf16_t*)alloc((size_t)SEQ * DIM * 2);
    bf16_t* Wqkvb = (bf16_t*)alloc((size_t)3 * DIM * DIM * 2);
    bf16_t* Wob   = (bf16_t*)alloc((size_t)DIM * DIM * 2);
    float*  bqkv  = (float*)alloc(3072 * 4);
    bf16_t* QKV   = (bf16_t*)alloc((size_t)SEQ * 3 * DIM * 2);
    bf16_t* Qhp   = (bf16_t*)alloc((size_t)SEQ * DIM * 2);
    bf16_t* Khp   = (bf16_t*)alloc((size_t)SEQ * DIM * 2);
    bf16_t* Vt    = (bf16_t*)alloc((size_t)DIM * SEQ * 2);
    float*  zsq   = (float*)alloc((size_t)NH * SEQ * 4);
    bf16_t* Opart = (bf16_t*)alloc((size_t)NH * SEQ * SPLIT * HD * 2);
    float*  Lpart = (float*)alloc((size_t)NH * SEQ * SPLIT * 4);
    bf16_t* WVb   = (bf16_t*)alloc((size_t)SEQ * DIM * 2);
    int*    mflag = (int*)alloc(256);

    float* outp = (float*)d_out;
    float* qkp  = outp + (size_t)SEQ * DIM;   // out is 2048*1024, then qk 16*2048*2048

    k_tables<<<256, 256, 0, stream>>>(invf, bq, bv, cosT, sinT, bqkv, mflag);
    k_cvt_all<<<10240, 256, 0, stream>>>(x, Wq, Wk, Wv, Wo, mask, Xb, Wqkvb, Wob, mflag);

    // fused QKV projection: [2048][3072]
    gemm128<<<dim3(SEQ / 128, 3072 / 128), 256, 0, stream>>>(Xb, Wqkvb, bqkv, QKV, nullptr, 3072, DIM);

    k_ropeT<<<4608, 256, 0, stream>>>(QKV, cosT, sinT, Zf, Qhp, Khp, zsq, Vt);

    k_attn<<<NH * (SEQ / 64) * SPLIT, 256, 0, stream>>>(Qhp, Khp, Vt, mask, zsq, mflag,
                                                        qkp, Opart, Lpart);
    k_combine<<<(NH * SEQ * HD) / 256, 256, 0, stream>>>(Opart, Lpart, WVb);

    // output projection (f32 out)
    gemm128<<<dim3(SEQ / 128, DIM / 128), 256, 0, stream>>>(WVb, Wob, bo, nullptr, outp, DIM, DIM);
}